// Round 11
// baseline (4895.698 us; speedup 1.0000x reference)
//
#include <hip/hip_runtime.h>

// ---------------------------------------------------------------------------
// VRAE LSTM: B=512, T=512, HE=HD=512, L=64.
// Round 11 = round-10 single-phase structure + gen-tag protocol (no drain,
// no flags: consumers spin on (gen16|f16) tagged h words), coalesced tagged
// stores, decoder heads off-chain (overlap next spin), LDS h double-buffer.
// 32 groups (16 rows) x 8 WGs (64 units, 512 thr, 8 waves). U packed f16 in
// ws, asm-loaded (resident in unified VGPR/AGPR file).
// ---------------------------------------------------------------------------

#define B_   512
#define T_   512
#define H_   512
#define NGR  32   // groups
#define WPG  8    // WGs per group
#define RPG  16   // batch rows per group
#define UPW  64   // units per WG

typedef _Float16 f16;
typedef _Float16 f16x8 __attribute__((ext_vector_type(8)));
typedef float f32x16 __attribute__((ext_vector_type(16)));
typedef unsigned long long u64;
typedef unsigned int u32;

// d_out floats: mu_dec[512*512] | sg_dec[512*512] | mu_enc[512*64] | sg_enc[512*64]
#define OFF_SG_DEC 262144
#define OFF_MU_ENC 524288
#define OFF_SG_ENC 557056

__device__ __forceinline__ float sigm_(float x) { return 1.f / (1.f + __expf(-x)); }
__device__ __forceinline__ float tanh_(float x) {
  float t = fabsf(x);
  float e = __expf(2.f * t);
  float r = 1.f - 2.f / (e + 1.f);
  return x < 0.f ? -r : r;
}
__device__ __forceinline__ float softplus_(float x) {
  return fmaxf(x, 0.f) + log1pf(__expf(-fabsf(x)));
}
__device__ __forceinline__ int fresh_(u64 w, u32 g) {
  return ((u32)(w >> 48) == g) & (((u32)(w >> 16) & 0xffffu) == g);
}
__device__ __forceinline__ u32 packh_(u64 w) {
  return (u32)(w & 0xffffu) | (((u32)(w >> 32) & 0xffffu) << 16);
}

// ---------------------------------------------------------------------------
// Pack U [512][2048] f32 -> f16 fragment order:
// Upk[(((wg*8+w)*32+ks)<<9) + lane*8 + j] = U[ks*16+(lane>>5)*8+j][gcol],
//   gcol = gate*512 + wg*64 + w*8 + uu, uu=(lane&31)>>2, gate=lane&3.
// ---------------------------------------------------------------------------
__global__ void pack_U(const float* __restrict__ U, f16* __restrict__ Upk) {
  const int e = blockIdx.x * 256 + threadIdx.x;  // 2^20 elements exactly
  const int j = e & 7, lane = (e >> 3) & 63, ks = (e >> 9) & 31;
  const int w = (e >> 14) & 7, wg = (e >> 17) & 7;
  const int ccol = lane & 31, khalf = lane >> 5;
  const int uu = ccol >> 2, gate = ccol & 3;
  const int k = ks * 16 + khalf * 8 + j;
  const int gcol = gate * 512 + wg * UPW + w * 8 + uu;
  Upk[e] = (f16)U[k * 2048 + gcol];
}

// ---------------------------------------------------------------------------
// IS_DEC=0: xin=[B][T] input (LDS-staged once), wa=enc_W, wb=enc_b
// IS_DEC=1: xin=zin [B][2048] incl bias, wa=dmu_W, wb=dstd_W
// hbuf: u32 [2][512][512] gen-tagged h (gen16|f16).
// ---------------------------------------------------------------------------
template <int IS_DEC>
__global__ void __launch_bounds__(512, 1)
lstm_rec(const f16* __restrict__ Upk,
         const float* __restrict__ xin,
         const float* __restrict__ wa,
         const float* __restrict__ wb,
         u32* __restrict__ hbuf,
         float* __restrict__ accmu,
         float* __restrict__ accsg) {
  const int bid = blockIdx.x;
  // XCD-local: a group's 8 WGs share bid%8 -> one XCD.
  const int wg = (bid >> 3) & 7;
  const int g = (bid & 7) * 4 + (bid >> 6);  // 0..31
  const int tid = threadIdx.x;
  const int wave = tid >> 6, lane = tid & 63;
  const int R0 = g * RPG;    // global batch-row base
  const int U0 = wg * UPW;   // unit base
  const u32 GB = IS_DEC ? 0x8000u : 0u;

  // ---- Breg from packed U: asm loads (non-remat, resident) ----------------
  const int ccol = lane & 31, khalf = lane >> 5;
  f16x8 Breg[32];
#pragma unroll
  for (int ks = 0; ks < 32; ++ks) {
    const f16* p = Upk + (((wg * 8 + wave) * 32 + ks) << 9) + lane * 8;
    asm volatile("global_load_dwordx4 %0, %1, off\n\ts_waitcnt vmcnt(0)"
                 : "=v"(Breg[ks]) : "v"(p));
  }

  // ---- per-thread elementwise mapping (tid<256 active) --------------------
  const int row = tid >> 4;        // 0..15 for active threads
  const int q = (tid & 15) * 4;    // first of 4 units
  float addv[16], xw[16];
  if (tid < 256) {
#pragma unroll
    for (int m = 0; m < 4; ++m) {
#pragma unroll
      for (int gt = 0; gt < 4; ++gt) {
        const int col = gt * 512 + U0 + q + m;
        if (IS_DEC) {
          addv[m * 4 + gt] = xin[(R0 + row) * 2048 + col];
          xw[m * 4 + gt] = 0.f;
        } else {
          addv[m * 4 + gt] = wb[col];
          xw[m * 4 + gt] = wa[col];
        }
      }
    }
  }
  // head weight slices (full 512-unit row; used by waves 0-1)
  float wmu[8], wsg[8];
  if (IS_DEC) {
#pragma unroll
    for (int j = 0; j < 8; ++j) {
      wmu[j] = wa[lane * 8 + j];
      wsg[j] = wb[lane * 8 + j];
    }
  }

  float cst[4] = {0.f, 0.f, 0.f, 0.f};

  __shared__ __align__(16) f16 hstage[2][RPG * 536];  // 2 x 17,152 B
  __shared__ float gatesLds[RPG * 260];               // 16,640 B
  __shared__ float xl[RPG * 516];                     // 33,024 B (encoder x)

  if (!IS_DEC) {
#pragma unroll
    for (int i = 0; i < 16; ++i) {
      const int idx = tid + i * 512;
      const int r = idx >> 9, c2 = idx & 511;
      xl[r * 516 + c2] = xin[(R0 + r) * T_ + c2];
    }
    __syncthreads();
  }

  // staging: 8 u64/thread of the [16 rows][256 u64] tile
  int srow[8], scol[8], gidx[8];
#pragma unroll
  for (int i = 0; i < 8; ++i) {
    const int w = tid + i * 512;
    srow[i] = w >> 8; scol[i] = w & 255;   // 256 u64 per 512-u32 row
    gidx[i] = (R0 + srow[i]) * 256 + scol[i];
  }
  const u64* hb64 = (const u64*)hbuf;
  const int hrow = lane & 15;  // MFMA A row

  // prologue prefetch from buf0 (memset zeros = gen 0 for enc; dec_prep wrote
  // gen 0x8000 for dec)
  u64 wr[8];
#pragma unroll
  for (int i = 0; i < 8; ++i)
    wr[i] = __hip_atomic_load(hb64 + gidx[i], __ATOMIC_RELAXED,
                              __HIP_MEMORY_SCOPE_AGENT);
  asm volatile("" ::: "memory");

  for (int t = 0; t < T_; ++t) {
    const int b0 = (t & 1) * 131072;          // u64 offset, read buffer
    const int b1 = ((t + 1) & 1) * 131072;    // u64 offset, next buffer
    const int c1 = ((t + 1) & 1) * 262144;    // u32 offset, write buffer
    const u32 gr = GB + (u32)t, gn = gr + 1u;

    // ------------------ spin until this thread's 8 words fresh -----------
    for (;;) {
      int f = 1;
#pragma unroll
      for (int i = 0; i < 8; ++i) f &= fresh_(wr[i], gr);
      if (f) break;
#pragma unroll
      for (int i = 0; i < 8; ++i)
        wr[i] = __hip_atomic_load(hb64 + b0 + gidx[i], __ATOMIC_RELAXED,
                                  __HIP_MEMORY_SCOPE_AGENT);
    }
    f16* const sb = hstage[t & 1];
#pragma unroll
    for (int i = 0; i < 8; ++i)
      *(u32*)&sb[srow[i] * 536 + scol[i] * 2] = packh_(wr[i]);
    __syncthreads();

    // ------------------ gates = h @ U (MFMA 32x32x16, B in regs) ---------
    f32x16 acc;
#pragma unroll
    for (int j = 0; j < 16; ++j) acc[j] = 0.f;
#pragma unroll
    for (int ks = 0; ks < 32; ++ks) {
      f16x8 a = *(const f16x8*)&sb[hrow * 536 + ks * 16 + khalf * 8];
      acc = __builtin_amdgcn_mfma_f32_32x32x16_f16(a, Breg[ks], acc, 0, 0, 0);
    }
    // C rows 0..15 live in regs 0..7 (row=(r&3)+8*(r>>2)+4*khalf)
#pragma unroll
    for (int r = 0; r < 8; ++r) {
      const int orow = (r & 3) + 8 * (r >> 2) + 4 * khalf;
      gatesLds[orow * 260 + wave * 32 + ccol] = acc[r];
    }
    __syncthreads();

    // ------------------ elementwise LSTM update (tid<256) ----------------
    if (tid < 256) {
      float xv = 0.f;
      if (!IS_DEC) xv = xl[row * 516 + t];
      float hn[4];
#pragma unroll
      for (int m = 0; m < 4; ++m) {
        float ga[4];
#pragma unroll
        for (int gt = 0; gt < 4; ++gt) {
          float v = gatesLds[row * 260 + (q + m) * 4 + gt] + addv[m * 4 + gt];
          if (!IS_DEC) v += xv * xw[m * 4 + gt];
          ga[gt] = v;
        }
        const float iv = sigm_(ga[0]);
        const float fv = sigm_(ga[1]);
        const float gv = tanh_(ga[2]);
        const float ov = sigm_(ga[3]);
        const float cn = fv * cst[m] + iv * gv;
        cst[m] = cn;
        hn[m] = ov * tanh_(cn);
      }
      // tagged stores: 4 units = 2 x u64 (16B contiguous/thread, coalesced)
      union { f16 h; unsigned short u; } hc0, hc1, hc2, hc3;
      hc0.h = (f16)hn[0]; hc1.h = (f16)hn[1];
      hc2.h = (f16)hn[2]; hc3.h = (f16)hn[3];
      const u64 tg = (u64)gn << 16;
      const u64 w0 = (tg | hc0.u) | (((tg | hc1.u)) << 32);
      const u64 w1 = (tg | hc2.u) | (((tg | hc3.u)) << 32);
      u64* hdst = (u64*)(hbuf + c1 + (R0 + row) * 512 + U0 + q);
      __hip_atomic_store(hdst, w0, __ATOMIC_RELAXED, __HIP_MEMORY_SCOPE_AGENT);
      __hip_atomic_store(hdst + 1, w1, __ATOMIC_RELAXED, __HIP_MEMORY_SCOPE_AGENT);
    }

    // ------------------ prefetch next step (producers storing ~now) ------
#pragma unroll
    for (int i = 0; i < 8; ++i)
      wr[i] = __hip_atomic_load(hb64 + b1 + gidx[i], __ATOMIC_RELAXED,
                                __HIP_MEMORY_SCOPE_AGENT);
    asm volatile("" ::: "memory");

    // ------------------ decoder heads for output t-1 (off-chain) ---------
    // rows 2wg+wave (waves 0-1) from the staged h(t) tile; plain stores.
    if (IS_DEC && t >= 1 && wave < 2) {
      const int hr = 2 * wg + wave;
      const f16x8 hv = *(const f16x8*)&sb[hr * 536 + lane * 8];
      float smu = 0.f, ssg = 0.f;
#pragma unroll
      for (int j = 0; j < 8; ++j) {
        const float hq = (float)hv[j];
        smu += hq * wmu[j]; ssg += hq * wsg[j];
      }
#pragma unroll
      for (int o = 32; o; o >>= 1) {
        smu += __shfl_xor(smu, o); ssg += __shfl_xor(ssg, o);
      }
      if (lane == 0) {
        accmu[(R0 + hr) * 512 + (t - 1)] = smu;
        accsg[(R0 + hr) * 512 + (t - 1)] = ssg;
      }
    }
  }
}

// ---------------------------------------------------------------------------
// Decoder tail: mu/sg[., 511] from final h (buffer 0, gen 0x8000+512).
// ---------------------------------------------------------------------------
__global__ void dec_tail(const u32* __restrict__ hbuf, const float* __restrict__ dmuW,
                         const float* __restrict__ dstdW, float* __restrict__ accmu,
                         float* __restrict__ accsg) {
  const int r = blockIdx.x, lane = threadIdx.x;  // 64 threads
  float smu = 0.f, ssg = 0.f;
#pragma unroll
  for (int j = 0; j < 8; ++j) {
    union { unsigned short u; f16 h; } c;
    c.u = (unsigned short)(hbuf[r * 512 + lane * 8 + j] & 0xffffu);
    const float hq = (float)c.h;
    smu += hq * dmuW[lane * 8 + j];
    ssg += hq * dstdW[lane * 8 + j];
  }
#pragma unroll
  for (int o = 32; o; o >>= 1) {
    smu += __shfl_xor(smu, o); ssg += __shfl_xor(ssg, o);
  }
  if (lane == 0) {
    accmu[r * 512 + 511] = smu;
    accsg[r * 512 + 511] = ssg;
  }
}

// ---------------------------------------------------------------------------
__global__ void enc_heads(const u32* __restrict__ h0, const float* __restrict__ emuW,
                          const float* __restrict__ emub, const float* __restrict__ estdW,
                          const float* __restrict__ estdb, float* __restrict__ out,
                          float* __restrict__ z) {
  const int b = blockIdx.x, tid = threadIdx.x;
  __shared__ float hrow[512];
  for (int k = tid; k < 512; k += 128) {
    union { unsigned short u; f16 h; } c;
    c.u = (unsigned short)(h0[b * 512 + k] & 0xffffu);
    hrow[k] = (float)c.h;
  }
  __syncthreads();
  const int head = tid >> 6, l = tid & 63;
  const float* W = head ? estdW : emuW;
  float a = 0.f;
#pragma unroll 8
  for (int k = 0; k < 512; ++k) a += hrow[k] * W[k * 64 + l];
  if (head == 0) {
    const float v = a + emub[l];
    out[OFF_MU_ENC + b * 64 + l] = v;
    z[b * 64 + l] = v;
  } else {
    out[OFF_SG_ENC + b * 64 + l] = softplus_(a + estdb[l]);
  }
}

// ---------------------------------------------------------------------------
// Decoder prep: hd = tanh(z@dfs_W+dfs_b) -> hbuf buf0 (gen 0x8000);
//               zin = z@dec_W+dec_b
// ---------------------------------------------------------------------------
__global__ void dec_prep(const float* __restrict__ z, const float* __restrict__ dfsW,
                         const float* __restrict__ dfsb, const float* __restrict__ decW,
                         const float* __restrict__ decb, u32* __restrict__ hbuf,
                         float* __restrict__ zin) {
  const int b = blockIdx.x, tid = threadIdx.x;
  __shared__ float zl[64];
  if (tid < 64) zl[tid] = z[b * 64 + tid];
  __syncthreads();
  for (int c = tid; c < 512; c += 256) {
    float a = dfsb[c];
#pragma unroll
    for (int l = 0; l < 64; ++l) a += zl[l] * dfsW[l * 512 + c];
    union { f16 h; unsigned short u; } hc; hc.h = (f16)tanh_(a);
    hbuf[b * 512 + c] = (0x8000u << 16) | (u32)hc.u;
  }
  for (int c = tid; c < 2048; c += 256) {
    float a = decb[c];
#pragma unroll
    for (int l = 0; l < 64; ++l) a += zl[l] * decW[l * 2048 + c];
    zin[b * 2048 + c] = a;
  }
}

// ---------------------------------------------------------------------------
__global__ void finalize_k(const float* __restrict__ accmu, const float* __restrict__ accsg,
                           const float* __restrict__ dmub, const float* __restrict__ dstdb,
                           float* __restrict__ out) {
  const int i = blockIdx.x * 256 + threadIdx.x;
  out[i] = accmu[i] + dmub[0];
  out[OFF_SG_DEC + i] = softplus_(accsg[i] + dstdb[0]);
}

// ---------------------------------------------------------------------------
extern "C" void kernel_launch(void* const* d_in, const int* in_sizes, int n_in,
                              void* d_out, int out_size, void* d_ws, size_t ws_size,
                              hipStream_t stream) {
  (void)in_sizes; (void)n_in; (void)out_size; (void)ws_size;
  const float* x     = (const float*)d_in[0];
  const float* encW  = (const float*)d_in[1];
  const float* encU  = (const float*)d_in[2];
  const float* encb  = (const float*)d_in[3];
  const float* emuW  = (const float*)d_in[4];
  const float* emub  = (const float*)d_in[5];
  const float* estdW = (const float*)d_in[6];
  const float* estdb = (const float*)d_in[7];
  const float* dfsW  = (const float*)d_in[8];
  const float* dfsb  = (const float*)d_in[9];
  const float* decW  = (const float*)d_in[10];
  const float* decU  = (const float*)d_in[11];
  const float* decb  = (const float*)d_in[12];
  const float* dmuW  = (const float*)d_in[13];
  const float* dmub  = (const float*)d_in[14];
  const float* dstdW = (const float*)d_in[15];
  const float* dstdb = (const float*)d_in[16];

  char* ws = (char*)d_ws;
  u32*   hbuf  = (u32*)(ws + 0);                   // 2 MB: [2][512][512] u32
  float* accmu = (float*)(ws + (2u << 20));        // 1 MB
  float* accsg = (float*)(ws + (3u << 20));        // 1 MB
  f16*   UpkE  = (f16*)(ws + (4u << 20));          // 2 MB (dead after encoder)
  float* zin   = (float*)(ws + (4u << 20));        // 4 MB (overlays UpkE)
  f16*   UpkD  = (f16*)(ws + (8u << 20));          // 2 MB
  float* z     = (float*)(ws + (10u << 20));       // 128 KB
  float* out   = (float*)d_out;

  // zero hbuf (gen tags) every launch; acc fully rewritten by heads+tail.
  hipMemsetAsync(d_ws, 0, 2u << 20, stream);

  hipLaunchKernelGGL(pack_U, dim3(4096), dim3(256), 0, stream, encU, UpkE);
  hipLaunchKernelGGL(pack_U, dim3(4096), dim3(256), 0, stream, decU, UpkD);

  hipLaunchKernelGGL((lstm_rec<0>), dim3(256), dim3(512), 0, stream,
                     UpkE, x, encW, encb, hbuf, (float*)nullptr, (float*)nullptr);
  hipLaunchKernelGGL(enc_heads, dim3(512), dim3(128), 0, stream,
                     hbuf, emuW, emub, estdW, estdb, out, z);
  hipLaunchKernelGGL(dec_prep, dim3(512), dim3(256), 0, stream,
                     z, dfsW, dfsb, decW, decb, hbuf, zin);
  hipLaunchKernelGGL((lstm_rec<1>), dim3(256), dim3(512), 0, stream,
                     UpkD, zin, dmuW, dstdW, hbuf, accmu, accsg);
  hipLaunchKernelGGL(dec_tail, dim3(512), dim3(64), 0, stream,
                     hbuf, dmuW, dstdW, accmu, accsg);
  hipLaunchKernelGGL(finalize_k, dim3(1024), dim3(256), 0, stream,
                     accmu, accsg, dmub, dstdb, out);
}

// Round 12
// 4508.974 us; speedup vs baseline: 1.0858x; 1.0858x over previous
//
#include <hip/hip_runtime.h>

// ---------------------------------------------------------------------------
// VRAE LSTM: B=512, T=512, HE=HD=512, L=64.
// Round 12 hybrid: ENCODER = round-6 A/B-phase gen-tag kernel (measured best
// encoder, ~1.8ms); DECODER = round-10 single-phase flags kernel (measured
// best decoder, ~1.75ms). Separate h buffers/protocols per kernel.
// ---------------------------------------------------------------------------

#define B_   512
#define T_   512
#define H_   512
#define NGR  32
#define WPG  8
#define RPG  16
#define UPW  64

typedef _Float16 f16;
typedef _Float16 f16x8 __attribute__((ext_vector_type(8)));
typedef _Float16 f16x4 __attribute__((ext_vector_type(4)));
typedef float f32x16 __attribute__((ext_vector_type(16)));
typedef unsigned long long u64;
typedef unsigned int u32;

// d_out floats: mu_dec[512*512] | sg_dec[512*512] | mu_enc[512*64] | sg_enc[512*64]
#define OFF_SG_DEC 262144
#define OFF_MU_ENC 524288
#define OFF_SG_ENC 557056

__device__ __forceinline__ float sigm_(float x) { return 1.f / (1.f + __expf(-x)); }
__device__ __forceinline__ float tanh_(float x) {
  float t = fabsf(x);
  float e = __expf(2.f * t);
  float r = 1.f - 2.f / (e + 1.f);
  return x < 0.f ? -r : r;
}
__device__ __forceinline__ float softplus_(float x) {
  return fmaxf(x, 0.f) + log1pf(__expf(-fabsf(x)));
}
__device__ __forceinline__ int fresh_(u64 w, u32 g) {
  return ((u32)(w >> 48) == g) & (((u32)(w >> 16) & 0xffffu) == g);
}
__device__ __forceinline__ u32 packh_(u64 w) {
  return (u32)(w & 0xffffu) | (((u32)(w >> 32) & 0xffffu) << 16);
}

// ---------------------------------------------------------------------------
// Pack U [512][2048] f32 -> f16 fragment order (shared by both kernels).
// ---------------------------------------------------------------------------
__global__ void pack_U(const float* __restrict__ U, f16* __restrict__ Upk) {
  const int e = blockIdx.x * 256 + threadIdx.x;  // 2^20 elements exactly
  const int j = e & 7, lane = (e >> 3) & 63, ks = (e >> 9) & 31;
  const int w = (e >> 14) & 7, wg = (e >> 17) & 7;
  const int ccol = lane & 31, khalf = lane >> 5;
  const int uu = ccol >> 2, gate = ccol & 3;
  const int k = ks * 16 + khalf * 8 + j;
  const int gcol = gate * 512 + wg * UPW + w * 8 + uu;
  Upk[e] = (f16)U[k * 2048 + gcol];
}

// ---------------------------------------------------------------------------
// ENCODER (round-6 structure): 32 row-pairs (A=8 rows, B=8 rows) x 8 WGs.
// hbuf: u32 [2][512][512] gen-tagged (gen16|f16); per-phase 4-word spin.
// ---------------------------------------------------------------------------
__global__ void __launch_bounds__(512, 1)
lstm_enc(const f16* __restrict__ Upk,
         const float* __restrict__ xin,   // [B][T]
         const float* __restrict__ wa,    // enc_W [1][2048]
         const float* __restrict__ wb,    // enc_b [2048]
         u32* __restrict__ hbuf) {
  const int bid = blockIdx.x;
  const int s = bid >> 3;
  const int j = (bid & 7) * 4 + (s & 3);  // row-pair 0..31 (XCD-local)
  const int wg = s >> 2;                  // unit slice 0..7
  const int tid = threadIdx.x, wave = tid >> 6, lane = tid & 63;
  const int U0 = wg * 64;
  const int RA = j * 16, RB = j * 16 + 8;
  const int ccol = lane & 31, khalf = lane >> 5;

  f16x8 Breg[32];
#pragma unroll
  for (int ks = 0; ks < 32; ++ks) {
    const f16* p = Upk + (((wg * 8 + wave) * 32 + ks) << 9) + lane * 8;
    asm volatile("global_load_dwordx4 %0, %1, off\n\ts_waitcnt vmcnt(0)"
                 : "=v"(Breg[ks]) : "v"(p));
  }

  const int erow = tid >> 6, eu = tid & 63;
  float xwv[4], bias[4];
#pragma unroll
  for (int gt = 0; gt < 4; ++gt) {
    const int col = gt * 512 + U0 + eu;
    bias[gt] = wb[col];
    xwv[gt] = wa[col];
  }

  float cA = 0.f, cB = 0.f;

  __shared__ __align__(16) f16 bufA[8 * 520];
  __shared__ __align__(16) f16 bufB[8 * 520];
  __shared__ __align__(16) float gatesL[8 * 264];

  int lrow[4], lcol[4], gidxA[4], gidxB[4];
#pragma unroll
  for (int i = 0; i < 4; ++i) {
    const int w = tid + i * 512;
    lrow[i] = w >> 8; lcol[i] = w & 255;
    gidxA[i] = (RA + lrow[i]) * 256 + lcol[i];
    gidxB[i] = (RB + lrow[i]) * 256 + lcol[i];
  }
  const u64* hb64 = (const u64*)hbuf;

  u64 wAr[4], wBr[4];
#pragma unroll
  for (int i = 0; i < 4; ++i)
    wAr[i] = __hip_atomic_load(hb64 + gidxA[i], __ATOMIC_RELAXED,
                               __HIP_MEMORY_SCOPE_AGENT);
  asm volatile("" ::: "memory");

  for (int t = 0; t < T_; ++t) {
    const int b0 = (t & 1) * 131072;
    const int b1 = ((t + 1) & 1) * 131072;
    const int c1 = ((t + 1) & 1) * 262144;
    const u32 gr = (u32)t, gn = (u32)t + 1u;

    // ================= A phase =================
    while (!(fresh_(wAr[0], gr) & fresh_(wAr[1], gr) &
             fresh_(wAr[2], gr) & fresh_(wAr[3], gr))) {
#pragma unroll
      for (int i = 0; i < 4; ++i)
        wAr[i] = __hip_atomic_load(hb64 + b0 + gidxA[i], __ATOMIC_RELAXED,
                                   __HIP_MEMORY_SCOPE_AGENT);
    }
#pragma unroll
    for (int i = 0; i < 4; ++i)
      *(u32*)&bufA[lrow[i] * 520 + lcol[i] * 2] = packh_(wAr[i]);
    __syncthreads();  // BAR1

#pragma unroll
    for (int i = 0; i < 4; ++i)
      wBr[i] = __hip_atomic_load(hb64 + b0 + gidxB[i], __ATOMIC_RELAXED,
                                 __HIP_MEMORY_SCOPE_AGENT);
    asm volatile("" ::: "memory");

    {
      f32x16 acc;
#pragma unroll
      for (int q = 0; q < 16; ++q) acc[q] = 0.f;
#pragma unroll
      for (int ks = 0; ks < 32; ++ks) {
        f16x8 a = *(const f16x8*)&bufA[(lane & 7) * 520 + ks * 16 + khalf * 8];
        acc = __builtin_amdgcn_mfma_f32_32x32x16_f16(a, Breg[ks], acc, 0, 0, 0);
      }
#pragma unroll
      for (int r = 0; r < 4; ++r)
        gatesL[(r + 4 * khalf) * 264 + wave * 32 + ccol] = acc[r];
    }
    __syncthreads();  // BAR2

    {  // ---- ew A ----
      const float4 g4 = *(const float4*)&gatesL[erow * 264 + (eu >> 3) * 32 + (eu & 7) * 4];
      const float xv = xin[(RA + erow) * T_ + t];
      const float ga0 = g4.x + bias[0] + xv * xwv[0];
      const float ga1 = g4.y + bias[1] + xv * xwv[1];
      const float ga2 = g4.z + bias[2] + xv * xwv[2];
      const float ga3 = g4.w + bias[3] + xv * xwv[3];
      const float cn = sigm_(ga1) * cA + sigm_(ga0) * tanh_(ga2);
      cA = cn;
      const float hn = sigm_(ga3) * tanh_(cn);
      union { f16 h; unsigned short u; } hc; hc.h = (f16)hn;
      __hip_atomic_store(hbuf + c1 + (RA + erow) * 512 + U0 + eu,
                         (gn << 16) | (u32)hc.u, __ATOMIC_RELAXED,
                         __HIP_MEMORY_SCOPE_AGENT);
    }

    // ================= B phase =================
    while (!(fresh_(wBr[0], gr) & fresh_(wBr[1], gr) &
             fresh_(wBr[2], gr) & fresh_(wBr[3], gr))) {
#pragma unroll
      for (int i = 0; i < 4; ++i)
        wBr[i] = __hip_atomic_load(hb64 + b0 + gidxB[i], __ATOMIC_RELAXED,
                                   __HIP_MEMORY_SCOPE_AGENT);
    }
#pragma unroll
    for (int i = 0; i < 4; ++i)
      *(u32*)&bufB[lrow[i] * 520 + lcol[i] * 2] = packh_(wBr[i]);
    __syncthreads();  // BAR3

#pragma unroll
    for (int i = 0; i < 4; ++i)
      wAr[i] = __hip_atomic_load(hb64 + b1 + gidxA[i], __ATOMIC_RELAXED,
                                 __HIP_MEMORY_SCOPE_AGENT);
    asm volatile("" ::: "memory");

    {
      f32x16 acc;
#pragma unroll
      for (int q = 0; q < 16; ++q) acc[q] = 0.f;
#pragma unroll
      for (int ks = 0; ks < 32; ++ks) {
        f16x8 a = *(const f16x8*)&bufB[(lane & 7) * 520 + ks * 16 + khalf * 8];
        acc = __builtin_amdgcn_mfma_f32_32x32x16_f16(a, Breg[ks], acc, 0, 0, 0);
      }
#pragma unroll
      for (int r = 0; r < 4; ++r)
        gatesL[(r + 4 * khalf) * 264 + wave * 32 + ccol] = acc[r];
    }
    __syncthreads();  // BAR4

    {  // ---- ew B ----
      const float4 g4 = *(const float4*)&gatesL[erow * 264 + (eu >> 3) * 32 + (eu & 7) * 4];
      const float xv = xin[(RB + erow) * T_ + t];
      const float ga0 = g4.x + bias[0] + xv * xwv[0];
      const float ga1 = g4.y + bias[1] + xv * xwv[1];
      const float ga2 = g4.z + bias[2] + xv * xwv[2];
      const float ga3 = g4.w + bias[3] + xv * xwv[3];
      const float cn = sigm_(ga1) * cB + sigm_(ga0) * tanh_(ga2);
      cB = cn;
      const float hn = sigm_(ga3) * tanh_(cn);
      union { f16 h; unsigned short u; } hc; hc.h = (f16)hn;
      __hip_atomic_store(hbuf + c1 + (RB + erow) * 512 + U0 + eu,
                         (gn << 16) | (u32)hc.u, __ATOMIC_RELAXED,
                         __HIP_MEMORY_SCOPE_AGENT);
    }
  }
}

// ---------------------------------------------------------------------------
// DECODER (round-10 structure): 32 groups (16 rows) x 8 WGs; f16 hbuf,
// flags protocol (store-drain + per-WG flag + 8-flag s_sleep poll);
// heads via pmu/psg LDS partials + one unsafeAtomicAdd per row, off-chain.
// ---------------------------------------------------------------------------
__global__ void __launch_bounds__(512, 1)
lstm_dec(const f16* __restrict__ Upk,
         const float* __restrict__ zin,   // [B][2048] incl bias
         const float* __restrict__ wmu_,  // dmu_W [512]
         const float* __restrict__ wsg_,  // dstd_W [512]
         f16* __restrict__ hbuf,
         float* __restrict__ accmu,
         float* __restrict__ accsg,
         int* __restrict__ flags) {
  const int bid = blockIdx.x;
  const int wg = (bid >> 3) & 7;
  const int g = (bid & 7) * 4 + (bid >> 6);
  const int tid = threadIdx.x;
  const int wave = tid >> 6, lane = tid & 63;
  const int R0 = g * RPG;
  const int U0 = wg * UPW;

  const int ccol = lane & 31, khalf = lane >> 5;
  f16x8 Breg[32];
#pragma unroll
  for (int ks = 0; ks < 32; ++ks) {
    const f16* p = Upk + (((wg * 8 + wave) * 32 + ks) << 9) + lane * 8;
    asm volatile("global_load_dwordx4 %0, %1, off\n\ts_waitcnt vmcnt(0)"
                 : "=v"(Breg[ks]) : "v"(p));
  }

  const int row = tid >> 4;
  const int q = (tid & 15) * 4;
  float addv[16], dmur[4], dstdr[4];
  if (tid < 256) {
#pragma unroll
    for (int m = 0; m < 4; ++m) {
#pragma unroll
      for (int gt = 0; gt < 4; ++gt)
        addv[m * 4 + gt] = zin[(R0 + row) * 2048 + gt * 512 + U0 + q + m];
      dmur[m] = wmu_[U0 + q + m];
      dstdr[m] = wsg_[U0 + q + m];
    }
  }

  float cst[4] = {0.f, 0.f, 0.f, 0.f};

  __shared__ __align__(16) f16 hstage[RPG * 536];
  __shared__ float gatesLds[RPG * 260];
  __shared__ float pmuLds[RPG * 17];
  __shared__ float psgLds[RPG * 17];

  const int hrow = lane & 15;
  int* const myflag = &flags[(g * WPG + wg) * 32];
  int* const grpflags = &flags[(g * WPG) * 32];

  for (int t = 0; t < T_; ++t) {
    const u64* hsrc64 = (const u64*)(hbuf + (t & 1) * (B_ * H_) + R0 * H_);
#pragma unroll
    for (int i = 0; i < 4; ++i) {
      const int w = tid + i * 512;
      const int r = w >> 7, c8 = w & 127;
      u64 v = __hip_atomic_load(hsrc64 + w, __ATOMIC_RELAXED,
                                __HIP_MEMORY_SCOPE_AGENT);
      *(u64*)&hstage[r * 536 + c8 * 4] = v;
    }
    __syncthreads();

    f32x16 acc;
#pragma unroll
    for (int j = 0; j < 16; ++j) acc[j] = 0.f;
#pragma unroll
    for (int ks = 0; ks < 32; ++ks) {
      f16x8 a = *(const f16x8*)&hstage[hrow * 536 + ks * 16 + khalf * 8];
      acc = __builtin_amdgcn_mfma_f32_32x32x16_f16(a, Breg[ks], acc, 0, 0, 0);
    }
#pragma unroll
    for (int r = 0; r < 8; ++r) {
      const int orow = (r & 3) + 8 * (r >> 2) + 4 * khalf;
      gatesLds[orow * 260 + wave * 32 + ccol] = acc[r];
    }
    __syncthreads();

    union { f16x4 h4; u64 u; } cv;
    if (tid < 256) {
      float hn[4];
#pragma unroll
      for (int m = 0; m < 4; ++m) {
        float ga[4];
#pragma unroll
        for (int gt = 0; gt < 4; ++gt)
          ga[gt] = gatesLds[row * 260 + (q + m) * 4 + gt] + addv[m * 4 + gt];
        const float iv = sigm_(ga[0]);
        const float fv = sigm_(ga[1]);
        const float gv = tanh_(ga[2]);
        const float ov = sigm_(ga[3]);
        const float cn = fv * cst[m] + iv * gv;
        cst[m] = cn;
        hn[m] = ov * tanh_(cn);
      }
#pragma unroll
      for (int m = 0; m < 4; ++m) cv.h4[m] = (f16)hn[m];
      f16* hdst = hbuf + ((t + 1) & 1) * (B_ * H_) + (R0 + row) * H_ + U0 + q;
      __hip_atomic_store((u64*)hdst, cv.u, __ATOMIC_RELAXED,
                         __HIP_MEMORY_SCOPE_AGENT);
      float pmu = 0.f, psg = 0.f;
#pragma unroll
      for (int m = 0; m < 4; ++m) {
        pmu += (float)cv.h4[m] * dmur[m];
        psg += (float)cv.h4[m] * dstdr[m];
      }
      pmuLds[row * 17 + (tid & 15)] = pmu;
      psgLds[row * 17 + (tid & 15)] = psg;
    }

    asm volatile("s_waitcnt vmcnt(0)" ::: "memory");
    __syncthreads();
    if (t + 1 < T_ && tid == 0)
      __hip_atomic_store(myflag, t + 1, __ATOMIC_RELAXED,
                         __HIP_MEMORY_SCOPE_AGENT);

    if (tid < RPG) {
      float s = 0.f;
#pragma unroll
      for (int j = 0; j < 16; ++j) s += pmuLds[tid * 17 + j];
      unsafeAtomicAdd(&accmu[(R0 + tid) * T_ + t], s);
    } else if (tid < 2 * RPG) {
      const int rr = tid - RPG;
      float s = 0.f;
#pragma unroll
      for (int j = 0; j < 16; ++j) s += psgLds[rr * 17 + j];
      unsafeAtomicAdd(&accsg[(R0 + rr) * T_ + t], s);
    }

    if (t + 1 < T_) {
      if (tid < WPG) {
        while (__hip_atomic_load(&grpflags[tid * 32], __ATOMIC_RELAXED,
                                 __HIP_MEMORY_SCOPE_AGENT) < t + 1) {
          asm volatile("s_sleep 1");
        }
      }
      __syncthreads();
    }
  }
}

// ---------------------------------------------------------------------------
__global__ void enc_heads(const u32* __restrict__ h0, const float* __restrict__ emuW,
                          const float* __restrict__ emub, const float* __restrict__ estdW,
                          const float* __restrict__ estdb, float* __restrict__ out,
                          float* __restrict__ z) {
  const int b = blockIdx.x, tid = threadIdx.x;
  __shared__ float hrow[512];
  for (int k = tid; k < 512; k += 128) {
    union { unsigned short u; f16 h; } c;
    c.u = (unsigned short)(h0[b * 512 + k] & 0xffffu);
    hrow[k] = (float)c.h;
  }
  __syncthreads();
  const int head = tid >> 6, l = tid & 63;
  const float* W = head ? estdW : emuW;
  float a = 0.f;
#pragma unroll 8
  for (int k = 0; k < 512; ++k) a += hrow[k] * W[k * 64 + l];
  if (head == 0) {
    const float v = a + emub[l];
    out[OFF_MU_ENC + b * 64 + l] = v;
    z[b * 64 + l] = v;
  } else {
    out[OFF_SG_ENC + b * 64 + l] = softplus_(a + estdb[l]);
  }
}

// ---------------------------------------------------------------------------
__global__ void dec_prep(const float* __restrict__ z, const float* __restrict__ dfsW,
                         const float* __restrict__ dfsb, const float* __restrict__ decW,
                         const float* __restrict__ decb, f16* __restrict__ hbuf,
                         float* __restrict__ zin) {
  const int b = blockIdx.x, tid = threadIdx.x;
  __shared__ float zl[64];
  if (tid < 64) zl[tid] = z[b * 64 + tid];
  __syncthreads();
  for (int c = tid; c < 512; c += 256) {
    float a = dfsb[c];
#pragma unroll
    for (int l = 0; l < 64; ++l) a += zl[l] * dfsW[l * 512 + c];
    hbuf[b * H_ + c] = (f16)tanh_(a);
  }
  for (int c = tid; c < 2048; c += 256) {
    float a = decb[c];
#pragma unroll
    for (int l = 0; l < 64; ++l) a += zl[l] * decW[l * 2048 + c];
    zin[b * 2048 + c] = a;
  }
}

// ---------------------------------------------------------------------------
__global__ void finalize_k(const float* __restrict__ accmu, const float* __restrict__ accsg,
                           const float* __restrict__ dmub, const float* __restrict__ dstdb,
                           float* __restrict__ out) {
  const int i = blockIdx.x * 256 + threadIdx.x;
  out[i] = accmu[i] + dmub[0];
  out[OFF_SG_DEC + i] = softplus_(accsg[i] + dstdb[0]);
}

// ---------------------------------------------------------------------------
extern "C" void kernel_launch(void* const* d_in, const int* in_sizes, int n_in,
                              void* d_out, int out_size, void* d_ws, size_t ws_size,
                              hipStream_t stream) {
  (void)in_sizes; (void)n_in; (void)out_size; (void)ws_size;
  const float* x     = (const float*)d_in[0];
  const float* encW  = (const float*)d_in[1];
  const float* encU  = (const float*)d_in[2];
  const float* encb  = (const float*)d_in[3];
  const float* emuW  = (const float*)d_in[4];
  const float* emub  = (const float*)d_in[5];
  const float* estdW = (const float*)d_in[6];
  const float* estdb = (const float*)d_in[7];
  const float* dfsW  = (const float*)d_in[8];
  const float* dfsb  = (const float*)d_in[9];
  const float* decW  = (const float*)d_in[10];
  const float* decU  = (const float*)d_in[11];
  const float* decb  = (const float*)d_in[12];
  const float* dmuW  = (const float*)d_in[13];
  const float* dmub  = (const float*)d_in[14];
  const float* dstdW = (const float*)d_in[15];
  const float* dstdb = (const float*)d_in[16];

  char* ws = (char*)d_ws;
  u32*   hbufG = (u32*)(ws + 0);                       // 2 MB enc gen-tag h
  float* accmu = (float*)(ws + (2u << 20));            // 1 MB
  float* accsg = (float*)(ws + (3u << 20));            // 1 MB
  int*   flags = (int*)(ws + (4u << 20));              // 64 KB
  f16*   hbufF = (f16*)(ws + (4u << 20) + 65536);      // 1 MB dec f16 h
  f16*   UpkE  = (f16*)(ws + (5u << 20) + 65536);      // 2 MB (dead post-enc)
  float* zin   = (float*)(ws + (5u << 20) + 65536);    // 4 MB overlays UpkE
  f16*   UpkD  = (f16*)(ws + (9u << 20) + 65536);      // 2 MB
  float* z     = (float*)(ws + (11u << 20) + 65536);   // 128 KB
  float* out   = (float*)d_out;

  // zero enc gen-tags + decoder accumulators + flags (contiguous 4MB+64KB)
  hipMemsetAsync(d_ws, 0, (4u << 20) + 65536, stream);

  hipLaunchKernelGGL(pack_U, dim3(4096), dim3(256), 0, stream, encU, UpkE);
  hipLaunchKernelGGL(pack_U, dim3(4096), dim3(256), 0, stream, decU, UpkD);

  hipLaunchKernelGGL(lstm_enc, dim3(256), dim3(512), 0, stream,
                     UpkE, x, encW, encb, hbufG);
  hipLaunchKernelGGL(enc_heads, dim3(512), dim3(128), 0, stream,
                     hbufG, emuW, emub, estdW, estdb, out, z);
  hipLaunchKernelGGL(dec_prep, dim3(512), dim3(256), 0, stream,
                     z, dfsW, dfsb, decW, decb, hbufF, zin);
  hipLaunchKernelGGL(lstm_dec, dim3(256), dim3(512), 0, stream,
                     UpkD, zin, dmuW, dstdW, hbufF, accmu, accsg, flags);
  hipLaunchKernelGGL(finalize_k, dim3(1024), dim3(256), 0, stream,
                     accmu, accsg, dmub, dstdb, out);
}